// Round 9
// baseline (1564.954 us; speedup 1.0000x reference)
//
#include <hip/hip_runtime.h>

#define BB 100000
#define NN 20
#define ND 128
#define TD 64
#define CD 192
#define HD 128
#define NH 4
#define DH 32
#define NL 2
#define WLS 311296  // per-layer WF stride (u16): 608 tiles x 512

typedef __attribute__((ext_vector_type(8))) short bf16x8;
typedef __attribute__((ext_vector_type(4))) float f32x4;

static __device__ __forceinline__ float bf2f(unsigned short u) {
  return __uint_as_float(((unsigned)u) << 16);
}
static __device__ __forceinline__ unsigned short f2bf(float x) {
  unsigned b = __float_as_uint(x);
  return (unsigned short)((b + 0x7FFFu + ((b >> 16) & 1u)) >> 16);
}
static __device__ __forceinline__ bf16x8 load_a8(const float* p) {
  float4 a = *(const float4*)p, b = *(const float4*)(p + 4);
  bf16x8 r;
  r[0] = (short)f2bf(a.x); r[1] = (short)f2bf(a.y);
  r[2] = (short)f2bf(a.z); r[3] = (short)f2bf(a.w);
  r[4] = (short)f2bf(b.x); r[5] = (short)f2bf(b.y);
  r[6] = (short)f2bf(b.z); r[7] = (short)f2bf(b.w);
  return r;
}
// Pack (within-tile k=wk, col=c16) -> fragment element index (m89 layout).
static __device__ __forceinline__ int fragidx(int wk, int c16) {
  return (((wk >> 3) << 4) | c16) * 8 + (wk & 7);
}

// ---------------------------------------------------------------------------
// R9 pipeline. Weight folds (FLOPs free on MFMA; deletes y & ab round trips):
//   M[c1][h*192+c2] = sum_d Wq[c1][h*32+d] Wk[c2][h*32+d]   (r = qc@M + pk)
//   pk[h*192+c2]    = sum_d bq[h*32+d] Wk[c2][h*32+d]
//   WC[h*192+c][j]  = sum_d Wv[c][h*32+d] Wo[h*32+d][j]     (attn = u@WC + bC)
//   bC[j]           = bo[j] + sum_k bv[k] Wo[k][j]
// Per-layer WF tile map: M 0-287 (kt*48+nt), WC 288-479 (kt*8+nt),
// W1 480-543 (kt*16+nt), W2 544-607 (kt*8+nt).
// kcf dropped (tier A was net +0.5 GB traffic). Classifier fused into the
// final gemm_ln epilogue.
// ---------------------------------------------------------------------------

__global__ __launch_bounds__(192) void precomp_M(
    const float* __restrict__ Wq, const float* __restrict__ Wk,
    unsigned short* __restrict__ WF) {
  int e = blockIdx.x;               // (l*4+h)*192 + c1
  int c1 = e % CD;
  int h = (e / CD) % NH;
  int l = e / (CD * NH);
  int c2 = threadIdx.x;
  const float* wq = Wq + ((size_t)l * CD + c1) * HD + h * DH;
  const float* wk = Wk + ((size_t)l * CD + c2) * HD + h * DH;
  float acc = 0.f;
#pragma unroll
  for (int d = 0; d < DH; ++d) acc += wq[d] * wk[d];
  int n = h * CD + c2;
  int nt = n >> 4, c16 = n & 15;
  int kt = c1 >> 5, wk2 = c1 & 31;
  WF[(size_t)l * WLS + (size_t)(kt * 48 + nt) * 512 + fragidx(wk2, c16)] =
      f2bf(acc);
}

__global__ __launch_bounds__(192) void precomp_pk(
    const float* __restrict__ bq, const float* __restrict__ Wk,
    float* __restrict__ pk) {
  int e = blockIdx.x;  // l*4+h
  int h = e % NH, l = e / NH;
  int c2 = threadIdx.x;
  const float* bqp = bq + (size_t)l * HD + h * DH;
  const float* wk = Wk + ((size_t)l * CD + c2) * HD + h * DH;
  float acc = 0.f;
#pragma unroll
  for (int d = 0; d < DH; ++d) acc += bqp[d] * wk[d];
  pk[(size_t)l * 768 + h * CD + c2] = acc;
}

__global__ __launch_bounds__(128) void precomp_WC(
    const float* __restrict__ Wv, const float* __restrict__ Wo,
    unsigned short* __restrict__ WF) {
  int e = blockIdx.x;  // l*768 + k
  int k = e % 768, l = e / 768;
  int c = k % CD, h = k / CD;
  int j = threadIdx.x;
  const float* wv = Wv + ((size_t)l * CD + c) * HD + h * DH;
  const float* wo = Wo + ((size_t)l * HD + h * DH) * ND + j;
  float acc = 0.f;
#pragma unroll
  for (int d = 0; d < DH; ++d) acc += wv[d] * wo[(size_t)d * ND];
  int kt = k >> 5, wk2 = k & 31;
  int nt = j >> 4, c16 = j & 15;
  WF[(size_t)l * WLS + 147456 + (size_t)(kt * 8 + nt) * 512 +
     fragidx(wk2, c16)] = f2bf(acc);
}

__global__ __launch_bounds__(128) void precomp_bC(
    const float* __restrict__ bv, const float* __restrict__ bo,
    const float* __restrict__ Wo, float* __restrict__ bC) {
  int l = blockIdx.x;
  int j = threadIdx.x;
  float acc = bo[(size_t)l * ND + j];
  for (int k = 0; k < HD; ++k)
    acc += bv[(size_t)l * HD + k] * Wo[((size_t)l * HD + k) * ND + j];
  bC[(size_t)l * ND + j] = acc;
}

__global__ __launch_bounds__(256) void conv_w2(
    const float* __restrict__ W1, const float* __restrict__ W2,
    unsigned short* __restrict__ WF) {
  int t = blockIdx.x;            // 0..255
  int l = t >> 7, tt = t & 127;
#pragma unroll
  for (int e = 0; e < 2; ++e) {
    int idx = threadIdx.x * 2 + e;
    int lane = idx >> 3, j = idx & 7;
    int wk = ((lane >> 4) << 3) + j;
    int c16 = lane & 15;
    float v;
    size_t dst;
    if (tt < 64) {               // W1 [128x256]
      int kt = tt >> 4, n2 = tt & 15;
      v = W1[((size_t)l * ND + kt * 32 + wk) * (2 * ND) + n2 * 16 + c16];
      dst = (size_t)l * WLS + 245760 + (size_t)tt * 512 + idx;
    } else {                     // W2 [256x128]
      int t2 = tt - 64;
      int kt = t2 >> 3, n2 = t2 & 7;
      v = W2[((size_t)l * 2 * ND + kt * 32 + wk) * ND + n2 * 16 + c16];
      dst = (size_t)l * WLS + 278528 + (size_t)t2 * 512 + idx;
    }
    WF[dst] = f2bf(v);
  }
}

__global__ __launch_bounds__(256) void prep_tq(
    const float* __restrict__ ntime, const float* __restrict__ tf,
    const float* __restrict__ tp, float* __restrict__ tqf) {
  int i = blockIdx.x * 256 + threadIdx.x;
  int b = i >> 6, j = i & 63;
  tqf[i] = __cosf(ntime[b] * tf[j] + tp[j]);
}

__global__ __launch_bounds__(256) void prep_mb(const int* __restrict__ mask,
                                               unsigned* __restrict__ mb) {
  int e = blockIdx.x * 256 + threadIdx.x;
  if (e < BB) {
    unsigned m = 0;
    for (int n = 0; n < NN; ++n)
      m |= (mask[(size_t)e * NN + n] != 0 ? 1u : 0u) << n;
    mb[e] = m;
  }
}

// Generic 16-row-block GEMM. ABF: A bf16; OBF: out bf16. A2 = f32 concat
// source for k >= ksplit.
template <int TN, int ABF, int OBF>
__global__ __launch_bounds__(256) void gemm16(
    const void* __restrict__ A, int lda,
    const float* __restrict__ A2, int lda2, int ksplit,
    const unsigned short* __restrict__ BF,
    int ktiles, int ntiles,
    const float* __restrict__ bias,
    void* __restrict__ C, int ldc, int relu) {
  const int tid = threadIdx.x;
  const int wv = tid >> 6, lane = tid & 63;
  const int NW = blockDim.x >> 6;
  const int m0 = blockIdx.x << 4;
  const int arow = m0 + (lane & 15);
  const int kgrp = (lane >> 4) << 3;
  f32x4 acc[TN];
#pragma unroll
  for (int i = 0; i < TN; ++i) acc[i] = f32x4{0.f, 0.f, 0.f, 0.f};
  for (int kt = 0; kt < ktiles; ++kt) {
    bf16x8 af;
    if (kt * 32 >= ksplit) {
      af = load_a8(A2 + (size_t)arow * lda2 + (kt * 32 - ksplit) + kgrp);
    } else if (ABF) {
      af = *(const bf16x8*)((const unsigned short*)A + (size_t)arow * lda +
                            kt * 32 + kgrp);
    } else {
      af = load_a8((const float*)A + (size_t)arow * lda + kt * 32 + kgrp);
    }
#pragma unroll
    for (int i = 0; i < TN; ++i) {
      int nt = wv + NW * i;
      bf16x8 bf = *(const bf16x8*)(BF + (((size_t)(kt * ntiles + nt)) << 9) +
                                   (lane << 3));
      acc[i] = __builtin_amdgcn_mfma_f32_16x16x32_bf16(af, bf, acc[i], 0, 0, 0);
    }
  }
  const int crow = m0 + ((lane >> 4) << 2);
#pragma unroll
  for (int i = 0; i < TN; ++i) {
    int nt = wv + NW * i;
    int col = nt * 16 + (lane & 15);
    float bv = bias ? bias[col] : 0.f;
#pragma unroll
    for (int rr = 0; rr < 4; ++rr) {
      float v = acc[i][rr] + bv;
      if (relu) v = fmaxf(v, 0.f);
      if (OBF)
        ((unsigned short*)C)[(size_t)(crow + rr) * ldc + col] = f2bf(v);
      else
        ((float*)C)[(size_t)(crow + rr) * ldc + col] = v;
    }
  }
}

// GEMM (N=128) + bias + residual + LayerNorm -> xout f32. CLS=1: skip xout,
// run the classifier (relu(x@Wc1+bc1)@Wc2+bc2 -> sigmoid) from LDS instead.
template <int ABF, int CLS>
__global__ __launch_bounds__(256) void gemm_ln(
    const void* __restrict__ A, int lda, int ktiles,
    const unsigned short* __restrict__ BF,
    const float* __restrict__ bias, const float* __restrict__ res,
    const float* __restrict__ gamma, const float* __restrict__ beta,
    float* __restrict__ xout,
    const float* __restrict__ Wc1, const float* __restrict__ bc1,
    const float* __restrict__ Wc2, const float* __restrict__ bc2,
    float* __restrict__ out) {
  __shared__ float Cs[16][132];
  __shared__ float hsh[16][64];
  const int tid = threadIdx.x;
  const int wv = tid >> 6, lane = tid & 63;
  const int m0 = blockIdx.x << 4;
  const int arow = m0 + (lane & 15);
  const int kgrp = (lane >> 4) << 3;
  const int nt0 = wv, nt1 = wv + 4;
  f32x4 acc0 = {0.f, 0.f, 0.f, 0.f}, acc1 = {0.f, 0.f, 0.f, 0.f};
  for (int kt = 0; kt < ktiles; ++kt) {
    bf16x8 af;
    if (ABF)
      af = *(const bf16x8*)((const unsigned short*)A + (size_t)arow * lda +
                            kt * 32 + kgrp);
    else
      af = load_a8((const float*)A + (size_t)arow * lda + kt * 32 + kgrp);
    bf16x8 b0 = *(const bf16x8*)(BF + (((size_t)(kt * 8 + nt0)) << 9) + (lane << 3));
    bf16x8 b1 = *(const bf16x8*)(BF + (((size_t)(kt * 8 + nt1)) << 9) + (lane << 3));
    acc0 = __builtin_amdgcn_mfma_f32_16x16x32_bf16(af, b0, acc0, 0, 0, 0);
    acc1 = __builtin_amdgcn_mfma_f32_16x16x32_bf16(af, b1, acc1, 0, 0, 0);
  }
  {
    const int lrow = (lane >> 4) << 2;
    int c0 = nt0 * 16 + (lane & 15), c1 = nt1 * 16 + (lane & 15);
    float bv0 = bias[c0], bv1 = bias[c1];
#pragma unroll
    for (int rr = 0; rr < 4; ++rr) {
      Cs[lrow + rr][c0] = acc0[rr] + bv0;
      Cs[lrow + rr][c1] = acc1[rr] + bv1;
    }
  }
  __syncthreads();
#pragma unroll
  for (int rr = 0; rr < 4; ++rr) {
    int rw = wv * 4 + rr;
    size_t grow = (size_t)(m0 + rw) * ND;
    float y0 = Cs[rw][lane] + res[grow + lane];
    float y1 = Cs[rw][lane + 64] + res[grow + lane + 64];
    float s = y0 + y1, ss = y0 * y0 + y1 * y1;
#pragma unroll
    for (int off = 32; off > 0; off >>= 1) {
      s += __shfl_xor(s, off);
      ss += __shfl_xor(ss, off);
    }
    float mean = s * (1.f / ND);
    float var = ss * (1.f / ND) - mean * mean;
    float rstd = rsqrtf(var + 1e-5f);
    float x0 = (y0 - mean) * rstd * gamma[lane] + beta[lane];
    float x1 = (y1 - mean) * rstd * gamma[lane + 64] + beta[lane + 64];
    if (CLS) {
      Cs[rw][lane] = x0;
      Cs[rw][lane + 64] = x1;
    } else {
      xout[grow + lane] = x0;
      xout[grow + lane + 64] = x1;
    }
  }
  if (CLS) {
    __syncthreads();
#pragma unroll
    for (int rep = 0; rep < 4; ++rep) {
      int idx = rep * 256 + tid;
      int row = idx >> 6, j = idx & 63;
      float acc = 0.f;
      for (int c = 0; c < ND; ++c) acc += Cs[row][c] * Wc1[c * 64 + j];
      hsh[row][j] = fmaxf(acc + bc1[j], 0.f);
    }
    __syncthreads();
#pragma unroll
    for (int rr = 0; rr < 4; ++rr) {
      int row = wv * 4 + rr;
      float p = hsh[row][lane] * Wc2[lane];
#pragma unroll
      for (int off = 32; off > 0; off >>= 1) p += __shfl_xor(p, off);
      if (lane == 0)
        out[m0 + row] = 1.f / (1.f + expf(-(p + bc2[0])));
    }
  }
}

// Attention, 2 elements/block, kc computed in-kernel (nbf + cos time enc).
// r,u bf16; u aliases r (element-private; r staged to LDS first).
__global__ __launch_bounds__(256) void attn_b(
    const float* __restrict__ nbf, const float* __restrict__ nbt,
    const float* __restrict__ tf, const float* __restrict__ tp,
    const unsigned* __restrict__ mb, const unsigned short* __restrict__ r,
    unsigned short* __restrict__ u) {
  __shared__ __align__(16) unsigned short kcb[2][NN][200];
  __shared__ __align__(16) float rs[2][768];
  __shared__ __align__(16) float scs[2][NH][NN];
  __shared__ unsigned msks[2];
  const int tid = threadIdx.x;
  const size_t e0 = (size_t)blockIdx.x * 2;

  if (tid < 192) {
    uint4 v = *(const uint4*)(r + e0 * 768 + tid * 8);
    const unsigned short* pv = (const unsigned short*)&v;
    float* dst = &rs[0][0] + tid * 8;
#pragma unroll
    for (int k = 0; k < 8; ++k) dst[k] = bf2f(pv[k]);
  }
  for (int i = tid; i < 2 * NN * 32; i += 256) {
    int el = i / (NN * 32), rem = i % (NN * 32);
    int n = rem >> 5, cq = rem & 31;
    float4 v = *(const float4*)&nbf[((e0 + el) * NN + n) * ND + cq * 4];
    ushort4 o;
    o.x = f2bf(v.x); o.y = f2bf(v.y); o.z = f2bf(v.z); o.w = f2bf(v.w);
    *(ushort4*)&kcb[el][n][cq * 4] = o;
  }
  for (int i = tid; i < 2 * NN * 32; i += 256) {
    int el = i / (NN * 32), rem = i % (NN * 32);
    int n = rem >> 5, jp = (rem & 31) * 2;
    float t = nbt[(e0 + el) * NN + n];
    unsigned a = f2bf(__cosf(t * tf[jp] + tp[jp]));
    unsigned b = f2bf(__cosf(t * tf[jp + 1] + tp[jp + 1]));
    *(unsigned*)&kcb[el][n][ND + jp] = a | (b << 16);
  }
  if (tid < 2) msks[tid] = mb[e0 + tid];
  __syncthreads();
  if (tid < 2 * NH * NN) {
    int el = tid / (NH * NN), rem = tid % (NH * NN);
    int h = rem / NN, n = rem % NN;
    const float* rp = &rs[el][h * CD];
    const unsigned short* kp = &kcb[el][n][0];
    float acc = 0.f;
    for (int c = 0; c < CD; c += 4) {
      float4 rv = *(const float4*)&rp[c];
      ushort4 kv = *(const ushort4*)&kp[c];
      acc += rv.x * bf2f(kv.x) + rv.y * bf2f(kv.y) + rv.z * bf2f(kv.z) +
             rv.w * bf2f(kv.w);
    }
    scs[el][h][n] =
        ((msks[el] >> n) & 1u) ? acc * 0.17677669529663687f : -1e9f;
  }
  __syncthreads();
  if (tid < 2 * NH) {
    int el = tid >> 2, h = tid & 3;
    float mx = -3.4e38f;
#pragma unroll
    for (int n = 0; n < NN; ++n) mx = fmaxf(mx, scs[el][h][n]);
    float ev[NN], s = 0.f;
#pragma unroll
    for (int n = 0; n < NN; ++n) { ev[n] = __expf(scs[el][h][n] - mx); s += ev[n]; }
    float inv = 1.f / s;
#pragma unroll
    for (int n = 0; n < NN; ++n) scs[el][h][n] = ev[n] * inv;
  }
  __syncthreads();
  for (int i = tid; i < 2 * NH * (CD / 4); i += 256) {
    int el = i / (NH * 48), rem = i % (NH * 48);
    int h = rem / 48, cq = (rem % 48) * 4;
    float a0 = 0.f, a1 = 0.f, a2 = 0.f, a3 = 0.f;
#pragma unroll
    for (int n = 0; n < NN; ++n) {
      float w = scs[el][h][n];
      ushort4 kv = *(const ushort4*)&kcb[el][n][cq];
      a0 += w * bf2f(kv.x); a1 += w * bf2f(kv.y);
      a2 += w * bf2f(kv.z); a3 += w * bf2f(kv.w);
    }
    ushort4 o;
    o.x = f2bf(a0); o.y = f2bf(a1); o.z = f2bf(a2); o.w = f2bf(a3);
    *(ushort4*)&u[(e0 + el) * 768 + h * CD + cq] = o;
  }
}

// ---------------------------------------------------------------------------
// Tier C fallback (R5 fused kernel) if workspace is tiny.
// ---------------------------------------------------------------------------
#define G 2
#define T 256
#define KCS 196
#define RUS 772

__global__ __launch_bounds__(T, 4) void tgat_fused(
    const float* __restrict__ nf, const float* __restrict__ nbf,
    const float* __restrict__ nt, const float* __restrict__ nbt,
    const float* __restrict__ tf, const float* __restrict__ tp,
    const float* __restrict__ Wq, const float* __restrict__ bq,
    const float* __restrict__ Wk,
    const float* __restrict__ Wv, const float* __restrict__ bv,
    const float* __restrict__ Wo, const float* __restrict__ bo,
    const float* __restrict__ W1, const float* __restrict__ b1,
    const float* __restrict__ W2, const float* __restrict__ b2,
    const float* __restrict__ g1, const float* __restrict__ be1,
    const float* __restrict__ g2, const float* __restrict__ be2,
    const float* __restrict__ Wc1, const float* __restrict__ bc1,
    const float* __restrict__ Wc2, const float* __restrict__ bc2,
    const int* __restrict__ mask,
    float* __restrict__ out) {
  __shared__ __align__(16) unsigned short kc[G][NN][KCS];
  __shared__ __align__(16) float xs[G][ND];
  __shared__ __align__(16) float tqs[G][TD];
  __shared__ __align__(16) float ys[G][HD];
  __shared__ __align__(16) float rus[G][RUS];
  __shared__ __align__(16) float scs[G][NH][NN];
  __shared__ __align__(16) float h1s[G][2 * ND];
  __shared__ __align__(16) unsigned msks[G];
  float* asv = &h1s[0][0];
  const int tid = threadIdx.x;
  const int b0 = blockIdx.x * G;
  {
    int g = tid >> 7, j = tid & 127;
    xs[g][j] = nf[(b0 + g) * ND + j];
  }
  if (tid < G * TD) {
    int g = tid >> 6, j = tid & 63;
    tqs[g][j] = __cosf(nt[b0 + g] * tf[j] + tp[j]);
  }
  if (tid < G) {
    unsigned m = 0;
    for (int n = 0; n < NN; ++n)
      m |= (mask[(b0 + tid) * NN + n] != 0 ? 1u : 0u) << n;
    msks[tid] = m;
  }
  for (int idx = tid; idx < G * NN * (ND / 4); idx += T) {
    int g = idx / (NN * 32), rem = idx % (NN * 32);
    int n = rem >> 5, cq = rem & 31;
    float4 v = *(const float4*)&nbf[(((b0 + g) * NN + n) * ND) + cq * 4];
    ushort4 o;
    o.x = f2bf(v.x); o.y = f2bf(v.y); o.z = f2bf(v.z); o.w = f2bf(v.w);
    *(ushort4*)&kc[g][n][cq * 4] = o;
  }
  for (int idx = tid; idx < G * NN * TD; idx += T) {
    int g = idx / (NN * TD), rem = idx % (NN * TD);
    int n = rem >> 6, j = rem & 63;
    kc[g][n][ND + j] = f2bf(__cosf(nbt[(b0 + g) * NN + n] * tf[j] + tp[j]));
  }
  __syncthreads();
  const float scale = 0.17677669529663687f;
  for (int l = 0; l < NL; ++l) {
    {
      int g = tid >> 7, j = tid & 127;
      const float* wq = Wq + (l * CD) * HD + j;
      float acc = bq[l * HD + j];
      for (int c = 0; c < CD; c += 4) {
        float4 qv = (c < ND) ? *(const float4*)&xs[g][c]
                             : *(const float4*)&tqs[g][c - ND];
        acc += qv.x * wq[(c + 0) * HD] + qv.y * wq[(c + 1) * HD] +
               qv.z * wq[(c + 2) * HD] + qv.w * wq[(c + 3) * HD];
      }
      ys[g][j] = acc;
    }
    __syncthreads();
    for (int rep = 0; rep < 3; ++rep) {
      int i = rep * T + tid;
      int h = i / CD;
      int c2 = i - h * CD;
      const float* wk = Wk + (l * CD + c2) * HD + h * DH;
      const float* yp0 = &ys[0][h * DH];
      const float* yp1 = &ys[1][h * DH];
      float a0 = 0.f, a1 = 0.f;
#pragma unroll
      for (int d = 0; d < DH; d += 4) {
        float4 w4 = *(const float4*)&wk[d];
        float4 y0 = *(const float4*)&yp0[d];
        float4 y1 = *(const float4*)&yp1[d];
        a0 += y0.x * w4.x + y0.y * w4.y + y0.z * w4.z + y0.w * w4.w;
        a1 += y1.x * w4.x + y1.y * w4.y + y1.z * w4.z + y1.w * w4.w;
      }
      rus[0][i] = a0;
      rus[1][i] = a1;
    }
    __syncthreads();
    if (tid < G * NH * NN) {
      int g = tid / (NH * NN), rem = tid % (NH * NN);
      int h = rem / NN, n = rem % NN;
      const float* rp = &rus[g][h * CD];
      const unsigned short* kp = &kc[g][n][0];
      float acc = 0.f;
      for (int c = 0; c < CD; c += 4) {
        float4 rv = *(const float4*)&rp[c];
        ushort4 kv = *(const ushort4*)&kp[c];
        acc += rv.x * bf2f(kv.x) + rv.y * bf2f(kv.y) + rv.z * bf2f(kv.z) +
               rv.w * bf2f(kv.w);
      }
      scs[g][h][n] = ((msks[g] >> n) & 1u) ? acc * scale : -1e9f;
    }
    __syncthreads();
    if (tid < G * NH) {
      int g = tid / NH, h = tid % NH;
      float mx = -3.4e38f;
#pragma unroll
      for (int n = 0; n < NN; ++n) mx = fmaxf(mx, scs[g][h][n]);
      float ev[NN], s = 0.f;
#pragma unroll
      for (int n = 0; n < NN; ++n) { ev[n] = __expf(scs[g][h][n] - mx); s += ev[n]; }
      float inv = 1.f / s;
#pragma unroll
      for (int n = 0; n < NN; ++n) scs[g][h][n] = ev[n] * inv;
    }
    __syncthreads();
    for (int flat = tid; flat < G * NH * (CD / 4); flat += T) {
      int g = flat / (NH * 48), iq = flat % (NH * 48);
      int h = iq / 48, c = (iq % 48) * 4;
      const unsigned short* kp = &kc[g][0][0];
      float a0 = 0.f, a1 = 0.f, a2 = 0.f, a3 = 0.f;
#pragma unroll
      for (int n = 0; n < NN; ++n) {
        float w = scs[g][h][n];
        ushort4 kv = *(const ushort4*)&kp[n * KCS + c];
        a0 += w * bf2f(kv.x); a1 += w * bf2f(kv.y);
        a2 += w * bf2f(kv.z); a3 += w * bf2f(kv.w);
      }
      *(float4*)&rus[g][h * CD + c] = make_float4(a0, a1, a2, a3);
    }
    __syncthreads();
    {
      int j = tid & (HD - 1);
      int g = tid >> 7;
      int h = j >> 5;
      const float* wv = Wv + (l * CD) * HD + j;
      float acc = 0.f;
      for (int c = 0; c < CD; c += 4) {
        float4 uv = *(const float4*)&rus[g][h * CD + c];
        acc += uv.x * wv[(c + 0) * HD] + uv.y * wv[(c + 1) * HD] +
               uv.z * wv[(c + 2) * HD] + uv.w * wv[(c + 3) * HD];
      }
      asv[g * HD + j] = acc + bv[l * HD + j];
    }
    __syncthreads();
    {
      int j = tid & (ND - 1);
      int g = tid >> 7;
      const float* wo = Wo + (l * HD) * ND + j;
      float acc = 0.f;
      for (int c = 0; c < HD; c += 4) {
        float4 av = *(const float4*)&asv[g * HD + c];
        acc += av.x * wo[(c + 0) * ND] + av.y * wo[(c + 1) * ND] +
               av.z * wo[(c + 2) * ND] + av.w * wo[(c + 3) * ND];
      }
      rus[g][j] = acc + bo[l * ND + j];
    }
    __syncthreads();
    if (tid < G * 64) {
      int g = tid >> 6, lane = tid & 63;
      float y0 = xs[g][lane] + rus[g][lane];
      float y1 = xs[g][lane + 64] + rus[g][lane + 64];
      float s = y0 + y1, ss = y0 * y0 + y1 * y1;
#pragma unroll
      for (int off = 32; off > 0; off >>= 1) {
        s += __shfl_xor(s, off);
        ss += __shfl_xor(ss, off);
      }
      float mean = s * (1.f / ND);
      float var = ss * (1.f / ND) - mean * mean;
      float rstd = rsqrtf(var + 1e-5f);
      xs[g][lane] = (y0 - mean) * rstd * g1[l * ND + lane] + be1[l * ND + lane];
      xs[g][lane + 64] =
          (y1 - mean) * rstd * g1[l * ND + lane + 64] + be1[l * ND + lane + 64];
    }
    __syncthreads();
    {
      int j = tid;
      const float* w1p = W1 + (l * ND) * (2 * ND) + j;
      float acc0 = 0.f, acc1 = 0.f;
      for (int c = 0; c < ND; c += 4) {
        float w0 = w1p[(c + 0) * 2 * ND], wa = w1p[(c + 1) * 2 * ND],
              w2 = w1p[(c + 2) * 2 * ND], w3 = w1p[(c + 3) * 2 * ND];
        float4 x0 = *(const float4*)&xs[0][c];
        float4 x1 = *(const float4*)&xs[1][c];
        acc0 += x0.x * w0 + x0.y * wa + x0.z * w2 + x0.w * w3;
        acc1 += x1.x * w0 + x1.y * wa + x1.z * w2 + x1.w * w3;
      }
      float b1v = b1[l * 2 * ND + j];
      h1s[0][j] = fmaxf(acc0 + b1v, 0.f);
      h1s[1][j] = fmaxf(acc1 + b1v, 0.f);
    }
    __syncthreads();
    {
      int j = tid & (ND - 1);
      int g = tid >> 7;
      const float* w2p = W2 + (l * 2 * ND) * ND + j;
      float acc = 0.f;
      for (int c = 0; c < 2 * ND; c += 4) {
        float4 hv = *(const float4*)&h1s[g][c];
        acc += hv.x * w2p[(c + 0) * ND] + hv.y * w2p[(c + 1) * ND] +
               hv.z * w2p[(c + 2) * ND] + hv.w * w2p[(c + 3) * ND];
      }
      rus[g][j] = acc + b2[l * ND + j];
    }
    __syncthreads();
    if (tid < G * 64) {
      int g = tid >> 6, lane = tid & 63;
      float y0 = xs[g][lane] + rus[g][lane];
      float y1 = xs[g][lane + 64] + rus[g][lane + 64];
      float s = y0 + y1, ss = y0 * y0 + y1 * y1;
#pragma unroll
      for (int off = 32; off > 0; off >>= 1) {
        s += __shfl_xor(s, off);
        ss += __shfl_xor(ss, off);
      }
      float mean = s * (1.f / ND);
      float var = ss * (1.f / ND) - mean * mean;
      float rstd = rsqrtf(var + 1e-5f);
      xs[g][lane] = (y0 - mean) * rstd * g2[l * ND + lane] + be2[l * ND + lane];
      xs[g][lane + 64] =
          (y1 - mean) * rstd * g2[l * ND + lane + 64] + be2[l * ND + lane + 64];
    }
    __syncthreads();
  }
  if (tid < G * 64) {
    int j = tid & 63;
    int g = tid >> 6;
    const float* wc = Wc1 + j;
    float acc = 0.f;
    for (int c = 0; c < ND; c += 4) {
      float4 xv = *(const float4*)&xs[g][c];
      acc += xv.x * wc[(c + 0) * 64] + xv.y * wc[(c + 1) * 64] +
             xv.z * wc[(c + 2) * 64] + xv.w * wc[(c + 3) * 64];
    }
    ((float*)scs)[g * 64 + j] = fmaxf(acc + bc1[j], 0.f);
  }
  __syncthreads();
  if (tid < G * 64) {
    int g = tid >> 6, lane = tid & 63;
    float p = ((float*)scs)[g * 64 + lane] * Wc2[lane];
#pragma unroll
    for (int off = 32; off > 0; off >>= 1) p += __shfl_xor(p, off);
    if (lane == 0) {
      float z = p + bc2[0];
      out[b0 + g] = 1.f / (1.f + expf(-z));
    }
  }
}

extern "C" void kernel_launch(void* const* d_in, const int* in_sizes, int n_in,
                              void* d_out, int out_size, void* d_ws,
                              size_t ws_size, hipStream_t stream) {
  (void)in_sizes; (void)n_in; (void)out_size;
  const float* nf  = (const float*)d_in[0];
  const float* nbf = (const float*)d_in[1];
  const float* ntm = (const float*)d_in[2];
  const float* nbt = (const float*)d_in[3];
  const float* tf  = (const float*)d_in[4];
  const float* tp  = (const float*)d_in[5];
  const float* Wq  = (const float*)d_in[6];
  const float* bq  = (const float*)d_in[7];
  const float* Wk  = (const float*)d_in[8];
  // d_in[9] = bk: n-uniform score shift -> softmax-invariant -> dropped
  const float* Wv  = (const float*)d_in[10];
  const float* bv  = (const float*)d_in[11];
  const float* Wo  = (const float*)d_in[12];
  const float* bo  = (const float*)d_in[13];
  const float* W1  = (const float*)d_in[14];
  const float* b1  = (const float*)d_in[15];
  const float* W2  = (const float*)d_in[16];
  const float* b2  = (const float*)d_in[17];
  const float* g1  = (const float*)d_in[18];
  const float* be1 = (const float*)d_in[19];
  const float* g2  = (const float*)d_in[20];
  const float* be2 = (const float*)d_in[21];
  const float* Wc1 = (const float*)d_in[22];
  const float* bc1 = (const float*)d_in[23];
  const float* Wc2 = (const float*)d_in[24];
  const float* bc2 = (const float*)d_in[25];
  const int* mask  = (const int*)d_in[26];
  float* out = (float*)d_out;

  // Workspace (bytes):
  //   WF   0 .. 1,245,184  (2 layers x 608 tiles x 1 KB)
  //   pk   1,245,184 .. +6,144  = 1,251,328
  //   bC   1,251,328 .. +1,024  = 1,252,352
  //   mb   1,252,352 .. +400,000 = 1,652,352 (pad to 16 -> 1,652,352 ok)
  //   tqf  1,652,352 .. +25.6M  = 27,252,352
  //   rb   27,252,352 .. +153.6M = 180,852,352  (bf16; u aliases)
  //   h1b  180,852,352 .. +51.2M = 232,052,352  (bf16)
  //   xfb  232,052,352 .. +51.2M = 283,252,352  (f32)   <- NEED
  const size_t NEED = 283252352ull;
  if (ws_size >= NEED) {
    char* w = (char*)d_ws;
    unsigned short* WF = (unsigned short*)w;
    float* pk = (float*)(w + 1245184);
    float* bC = (float*)(w + 1251328);
    unsigned* mb = (unsigned*)(w + 1252352);
    float* tqf = (float*)(w + 1652352);
    unsigned short* rb = (unsigned short*)(w + 27252352);
    unsigned short* h1b = (unsigned short*)(w + 180852352);
    float* xfb = (float*)(w + 232052352);

    precomp_M<<<NL * NH * CD, CD, 0, stream>>>(Wq, Wk, WF);
    precomp_pk<<<NL * NH, CD, 0, stream>>>(bq, Wk, pk);
    precomp_WC<<<NL * 768, ND, 0, stream>>>(Wv, Wo, WF);
    precomp_bC<<<NL, ND, 0, stream>>>(bv, bo, Wo, bC);
    conv_w2<<<256, 256, 0, stream>>>(W1, W2, WF);
    prep_tq<<<25000, 256, 0, stream>>>(ntm, tf, tp, tqf);
    prep_mb<<<(BB + 255) / 256, 256, 0, stream>>>(mask, mb);

    const float* xsrc = nf;
    for (int l = 0; l < NL; ++l) {
      const unsigned short* WFl = WF + (size_t)l * WLS;
      // r = [x|tq] @ M + pk  (K=192, N=768, bf16 out)
      gemm16<12, 0, 1><<<6250, 256, 0, stream>>>(
          xsrc, ND, tqf, TD, 128, WFl, 6, 48, pk + l * 768, rb, 768, 0);
      // scores/softmax/u (u bf16 overwrites r, element-private)
      attn_b<<<50000, 256, 0, stream>>>(nbf, nbt, tf, tp, mb, rb, rb);
      // x = LN1(x + u @ WC + bC)  (K=768)
      gemm_ln<1, 0><<<6250, 256, 0, stream>>>(
          rb, 768, 24, WFl + 147456, bC + l * ND, xsrc, g1 + l * ND,
          be1 + l * ND, xfb, nullptr, nullptr, nullptr, nullptr, nullptr);
      // h1 = relu(x @ W1 + b1)  (bf16 out)
      gemm16<4, 0, 1><<<6250, 256, 0, stream>>>(
          xfb, ND, nullptr, 0, 1 << 30, WFl + 245760, 4, 16,
          b1 + l * 2 * ND, h1b, 2 * ND, 1);
      // x = LN2(x + h1 @ W2 + b2); final layer: fused classifier
      if (l == NL - 1)
        gemm_ln<1, 1><<<6250, 256, 0, stream>>>(
            h1b, 2 * ND, 8, WFl + 278528, b2 + l * ND, xfb, g2 + l * ND,
            be2 + l * ND, xfb, Wc1, bc1, Wc2, bc2, out);
      else
        gemm_ln<1, 0><<<6250, 256, 0, stream>>>(
            h1b, 2 * ND, 8, WFl + 278528, b2 + l * ND, xfb, g2 + l * ND,
            be2 + l * ND, xfb, nullptr, nullptr, nullptr, nullptr, nullptr);
      xsrc = xfb;
    }
  } else {
    tgat_fused<<<BB / G, T, 0, stream>>>(nf, nbf, ntm, nbt, tf, tp, Wq, bq, Wk,
                                         Wv, bv, Wo, bo, W1, b1, W2, b2, g1,
                                         be1, g2, be2, Wc1, bc1, Wc2, bc2,
                                         mask, out);
  }
}